// Round 16
// baseline (191.679 us; speedup 1.0000x reference)
//
#include <hip/hip_runtime.h>
#include <hip/hip_bf16.h>

// Problem constants
#define HEADS   12
#define HD      64
#define NTOK    197          // N_PATCH + 1
#define BATCH   64
#define M_TOK   (BATCH*NTOK) // 12608
#define DIMC    768
#define NPAIR   (NTOK*NTOK)  // 38809
#define MPAD    224          // key/m dimension padded to 7*32

typedef __attribute__((ext_vector_type(8))) short bf16x8;   // 8 bf16 (4 VGPRs)
typedef __attribute__((ext_vector_type(4))) short s16x4;
typedef __attribute__((ext_vector_type(4))) float f32x4;
typedef __attribute__((ext_vector_type(16))) float f32x16;  // 32x32 acc

// fp32 -> bf16 round-to-nearest-even
static __device__ __forceinline__ short f2bf(float f) {
    unsigned u = __float_as_uint(f);
    unsigned r = (u + 0x7FFFu + ((u >> 16) & 1u)) >> 16;
    return (short)r;
}
static __device__ __forceinline__ float bf2f(short s) {
    return __uint_as_float(((unsigned)(unsigned short)s) << 16);
}

// ---------------------------------------------------------------------------
// Kernel 0: merged prep — fp32->bf16 bulk convert of x/qkv_w/proj_w PLUS the
// rpbL gather (pre-swizzled into MFMA C-fragment order, bf16). One launch.
// ---------------------------------------------------------------------------
#define NX (M_TOK * DIMC)        // 9,682,944
#define NW (3 * DIMC * DIMC)     // 1,769,472
#define NP (DIMC * DIMC)         //   589,824
#define NRPB (HEADS * 13 * 56 * 64)          // 559,104
#define CVT_N   ((NX + NW + NP) / 4)         // 3,010,560 float4s
#define CVT_BLK ((CVT_N + 255) / 256)        // 11,760
#define RPB_BLK ((NRPB + 255) / 256)         // 2,184
__global__ void prep_kernel(const float* __restrict__ s0, short* __restrict__ d0,
                            const float* __restrict__ s1, short* __restrict__ d1,
                            const float* __restrict__ s2, short* __restrict__ d2,
                            const float* __restrict__ table,
                            const int* __restrict__ idx,
                            short* __restrict__ rpbl) {
    if (blockIdx.x < CVT_BLK) {
        int i = (blockIdx.x * 256 + threadIdx.x) * 4;
        const float* s; short* d;
        if (i < NX)                { s = s0 + i; d = d0 + i; }
        else if (i < NX + NW)      { s = s1 + (i - NX); d = d1 + (i - NX); }
        else if (i < NX + NW + NP) { s = s2 + (i - NX - NW); d = d2 + (i - NX - NW); }
        else return;
        const float4 v = *(const float4*)s;
        s16x4 b; b[0] = f2bf(v.x); b[1] = f2bf(v.y); b[2] = f2bf(v.z); b[3] = f2bf(v.w);
        *(s16x4*)d = b;
    } else {
        int i = (blockIdx.x - CVT_BLK) * 256 + threadIdx.x;
        if (i >= NRPB) return;
        const int lane = i & 63;
        const int q    = (i >> 6) % 56;
        const int rt   = ((i >> 6) / 56) % 13;
        const int h    = (i >> 6) / (56 * 13);
        const int rg = q / 14, mt = q - rg * 14;
        const int g = lane >> 4, c16 = lane & 15;
        const int n = rt * 16 + g * 4 + rg;
        const int m = mt * 16 + c16;
        float v = 0.f;
        if (n < NTOK && m < NTOK) v = table[idx[n * NTOK + m] * HEADS + h];
        rpbl[i] = f2bf(v);
    }
}

// ---------------------------------------------------------------------------
// GEMM building blocks v3: 128x128 tile, BK=64, 4 waves, 2-phase dbuf staging
// (R13/R15 proven sync), involution LDS swizzle — but the inner loop now uses
// v_mfma_f32_32x32x16_bf16: per K-step 16 MFMA @ 4096 FLOP/cy (vs 32 @ 3277)
// and HALF the ds_read_b128 count (a 32-row frag = one b128 per k-slice).
// A/B loaded with identical k-contiguous convention (k-permutation cancels);
// C/D layout col=lane&31, row=(reg&3)+8*(reg>>2)+4*(lane>>5)  [m74/m101].
// ---------------------------------------------------------------------------
#define STAGE(LA, LB, kt)                                                       \
    _Pragma("unroll")                                                           \
    for (int i = 0; i < 4; ++i) {                                               \
        __builtin_amdgcn_global_load_lds(                                       \
            (const __attribute__((address_space(1))) void*)(aptr[i] + (kt) * 64),\
            (__attribute__((address_space(3))) void*)&(LA)[(wv * 4 + i) * 512], \
            16, 0, 0);                                                          \
        __builtin_amdgcn_global_load_lds(                                       \
            (const __attribute__((address_space(1))) void*)(bptr[i] + (kt) * 64),\
            (__attribute__((address_space(3))) void*)&(LB)[(wv * 4 + i) * 512], \
            16, 0, 0);                                                          \
    }

#define COMPUTE(LA, LB)                                                         \
    _Pragma("unroll")                                                           \
    for (int ks = 0; ks < 4; ++ks) {                                            \
        bf16x8 af[2], bfr[2];                                                   \
        const int ch = ((((ks << 1) + kh) ^ l7) << 3);   /* swizzled chunk */   \
        _Pragma("unroll")                                                       \
        for (int i = 0; i < 2; ++i)                                             \
            af[i] = *(const bf16x8*)&(LA)[(wr * 64 + i * 32 + r31) * 64 + ch];  \
        _Pragma("unroll")                                                       \
        for (int j = 0; j < 2; ++j)                                             \
            bfr[j] = *(const bf16x8*)&(LB)[(wc * 64 + j * 32 + r31) * 64 + ch]; \
        _Pragma("unroll")                                                       \
        for (int i = 0; i < 2; ++i)                                             \
            _Pragma("unroll")                                                   \
            for (int j = 0; j < 2; ++j)                                         \
                acc[i][j] = __builtin_amdgcn_mfma_f32_32x32x16_bf16(            \
                    af[i], bfr[j], acc[i][j], 0, 0, 0);                         \
    }

// row within the wave's 64-row panel for acc register `reg`, half `kh`
#define CROW(i, reg) (wr * 64 + (i) * 32 + ((reg) & 3) + 8 * ((reg) >> 2) + 4 * kh)

// ---------------------------------------------------------------------------
// Kernel 1: QKV GEMM (bf16 in). q/k/v uniform per bn (0-5 q, 6-11 k, 12-17 v).
// All epilogue paths transpose through LDS (full-line stores, wave-uniform
// /197). Grid: 1782 flat blocks, m204 bijective XCD swizzle (q=222, r=6).
// ---------------------------------------------------------------------------
__global__ __launch_bounds__(256) void qkv_gemm_kernel(
    const short* __restrict__ xb, const short* __restrict__ wb,
    const float* __restrict__ qb, const float* __restrict__ vb,
    short* __restrict__ q_ws, short* __restrict__ k_ws,
    short* __restrict__ vt_ws) {
    __shared__ __align__(16) short lds_a0[128 * 64];
    __shared__ __align__(16) short lds_a1[128 * 64];
    __shared__ __align__(16) short lds_bb[2 * 128 * 64];   // b0 = +0, b1 = +8192
    const int tid  = threadIdx.x;
    const int lane = tid & 63;
    const int wv   = tid >> 6;           // 0..3
    const int wr   = wv >> 1, wc = wv & 1;
    // XCD-bijective decode: nwg=1782, q=222, r=6
    const int flat = blockIdx.x;
    const int xcd  = flat & 7, pos = flat >> 3;
    const int swz  = ((xcd < 6) ? xcd * 223 : 1338 + (xcd - 6) * 222) + pos;
    const int bm   = swz / 18, bn = swz - bm * 18;
    const int g    = lane >> 4, c16 = lane & 15;
    const int r31  = lane & 31, kh = lane >> 5, l7 = lane & 7;

    f32x16 acc[2][2] = {};

    const int lrow = lane >> 3;
    const int lcol = ((lane & 7) ^ lrow) * 8;     // inverse-swizzled source col
    const short* aptr[4];
    const short* bptr[4];
    #pragma unroll
    for (int i = 0; i < 4; ++i) {
        const int r  = (wv * 4 + i) * 8 + lrow;
        int gr = bm * 128 + r; if (gr > M_TOK - 1) gr = M_TOK - 1;
        aptr[i] = xb + (size_t)gr * DIMC + lcol;
        bptr[i] = wb + (size_t)(bn * 128 + r) * DIMC + lcol;
    }

    STAGE(lds_a0, lds_bb, 0);
    __syncthreads();
    #pragma unroll
    for (int kp = 0; kp < 6; ++kp) {
        STAGE(lds_a1, (lds_bb + 8192), 2 * kp + 1);
        COMPUTE(lds_a0, lds_bb);
        __syncthreads();
        if (kp < 5) { STAGE(lds_a0, lds_bb, 2 * kp + 2); }
        COMPUTE(lds_a1, (lds_bb + 8192));
        if (kp < 5) __syncthreads();
    }

    // epilogue via LDS transpose (Phase B streaming is MFMA-layout-independent)
    __syncthreads();                  // all waves done reading lds_bb
    short* t = lds_bb;
    if (bn < 12) {
        const int isq = (bn < 6);
        // Phase A: acc -> t[tok*128 + (col ^ ((tok>>2)&3)<<4)]  (+bias/scale)
        #pragma unroll
        for (int j = 0; j < 2; ++j) {
            const int col = wc * 64 + j * 32 + r31;
            const int r   = isq ? bn * 128 + col : bn * 128 + col - DIMC;
            const float bias = isq ? qb[r] : 0.0f;
            #pragma unroll
            for (int i = 0; i < 2; ++i)
                #pragma unroll
                for (int reg = 0; reg < 16; ++reg) {
                    const int tok = CROW(i, reg);
                    const int sw  = ((tok >> 2) & 3) << 4;
                    float val = acc[i][j][reg];
                    if (isq) val = (val + bias) * 0.125f;
                    t[tok * 128 + (col ^ sw)] = f2bf(val);
                }
        }
        __syncthreads();
        // Phase B: wave wv streams token rows wv*32..+31; lane = d; 128B stores.
        short* dst = isq ? q_ws : k_ws;
        const int rbase = isq ? bn * 128 : bn * 128 - DIMC;
        for (int tr = 0; tr < 32; ++tr) {
            const int tok = wv * 32 + tr;
            const int tt  = bm * 128 + tok;
            if (tt >= M_TOK) continue;
            const int bb = tt / NTOK, nn = tt - bb * NTOK;     // wave-uniform
            const int sw = ((tok >> 2) & 3) << 4;
            #pragma unroll
            for (int half = 0; half < 2; ++half) {
                const int col = half * 64 + lane;
                const int h   = (rbase + half * 64) >> 6;      // lane<64: no carry
                dst[(((size_t)bb * HEADS + h) * NTOK + nn) * HD + lane] =
                    t[tok * 128 + (col ^ sw)];
            }
        }
    } else {
        // v-block: Phase A: acc -> t[col*128 + (tok ^ (col&7)<<3)] (+bias).
        #pragma unroll
        for (int j = 0; j < 2; ++j) {
            const int col  = wc * 64 + j * 32 + r31;
            const int sw   = (col & 7) << 3;
            const float bias = vb[(bn - 12) * 128 + col];
            #pragma unroll
            for (int i = 0; i < 2; ++i)
                #pragma unroll
                for (int reg = 0; reg < 16; ++reg) {
                    const int tok = CROW(i, reg);
                    t[col * 128 + (tok ^ sw)] = f2bf(acc[i][j][reg] + bias);
                }
        }
        __syncthreads();
        // Phase B: wave wv streams cols wv,wv+4,...; 64 lanes = 64 consecutive
        // tokens -> contiguous 128B stores.
        for (int cc = 0; cc < 32; ++cc) {
            const int col = cc * 4 + wv;
            const int sw  = (col & 7) << 3;
            const int r   = bn * 128 + col - 1536;
            const int h   = r >> 6, d = r & 63;
            #pragma unroll
            for (int half = 0; half < 2; ++half) {
                const int lt = lane + half * 64;
                const int tt = bm * 128 + lt;
                if (tt < M_TOK) {
                    const int b = tt / NTOK, n = tt - b * NTOK;
                    vt_ws[(((size_t)b * HEADS + h) * HD + d) * MPAD + n] =
                        t[col * 128 + (lt ^ sw)];
                }
            }
        }
    }
}

// ---------------------------------------------------------------------------
// Kernel 2: attention (R15). 4 independent waves per 256-thread block; XCD
// locality decode; register-batched K / rpbL / V loads; T5 setprio around
// MFMA clusters; O via LDS transpose. grid = 2496 = 312 * 8.
// ---------------------------------------------------------------------------
__global__ __launch_bounds__(256) void attn_kernel(
    const short* __restrict__ q_ws, const short* __restrict__ k_ws,
    const short* __restrict__ vt_ws, const short* __restrict__ rpbL,
    short* __restrict__ o_ws) {
    __shared__ __align__(16) short p_lds[4 * 3712];   // 4 slabs of 16*232
    const int lane = threadIdx.x & 63;
    const int wv   = threadIdx.x >> 6;
    const int id   = blockIdx.x;
    const int slot = id & 7;                          // XCD slot
    const int w    = (id >> 3) * 4 + wv;              // 0..1247 within slot
    const int bhl  = w / 13;                          // 0..95
    const int rt   = w - bhl * 13;                    // 0..12
    const int bh   = bhl * 8 + slot;                  // 0..767 (bijective)
    const int b    = bh / HEADS, h = bh - b * HEADS;
    const int g    = lane >> 4, c16 = lane & 15;
    short* p_base = p_lds + wv * 3712;

    bf16x8 qa0, qa1;
    {
        const size_t base = ((size_t)bh * NTOK + (rt * 16 + c16)) * HD + g * 8;
        qa0 = *(const bf16x8*)(q_ws + base);
        qa1 = *(const bf16x8*)(q_ws + base + 32);
    }

    // batch 1: all 28 K fragments (independent -> one latency)
    bf16x8 kb0[14], kb1[14];
    #pragma unroll
    for (int mt = 0; mt < 14; ++mt) {
        const size_t base = ((size_t)bh * NTOK + (mt * 16 + c16)) * HD + g * 8;
        kb0[mt] = *(const bf16x8*)(k_ws + base);
        kb1[mt] = *(const bf16x8*)(k_ws + base + 32);
    }

    f32x4 sacc[14];
    #pragma unroll
    for (int t = 0; t < 14; ++t) sacc[t] = (f32x4){0.f, 0.f, 0.f, 0.f};
    __builtin_amdgcn_s_setprio(1);
    #pragma unroll
    for (int mt = 0; mt < 14; ++mt) {
        sacc[mt] = __builtin_amdgcn_mfma_f32_16x16x32_bf16(qa0, kb0[mt], sacc[mt], 0, 0, 0);
        sacc[mt] = __builtin_amdgcn_mfma_f32_16x16x32_bf16(qa1, kb1[mt], sacc[mt], 0, 0, 0);
    }
    __builtin_amdgcn_s_setprio(0);

    // batch 2: 56 coalesced bf16 rpb lines (pre-swizzled to C-frag layout)
    float rp[4][14];
    {
        const short* rb = rpbL + (((size_t)h * 13 + rt) * 56) * 64 + lane;
        #pragma unroll
        for (int rg = 0; rg < 4; ++rg)
            #pragma unroll
            for (int mt = 0; mt < 14; ++mt)
                rp[rg][mt] = bf2f(rb[(rg * 14 + mt) * 64]);
    }

    float mx[4] = {-1e30f, -1e30f, -1e30f, -1e30f};
    #pragma unroll
    for (int rg = 0; rg < 4; ++rg) {
        const int n = rt * 16 + g * 4 + rg;
        #pragma unroll
        for (int mt = 0; mt < 14; ++mt) {
            const int m = mt * 16 + c16;
            float s = (n < NTOK && m < NTOK) ? sacc[mt][rg] + rp[rg][mt] : -1e30f;
            sacc[mt][rg] = s;
            mx[rg] = fmaxf(mx[rg], s);
        }
    }
    #pragma unroll
    for (int off = 1; off < 16; off <<= 1)
        #pragma unroll
        for (int rg = 0; rg < 4; ++rg)
            mx[rg] = fmaxf(mx[rg], __shfl_xor(mx[rg], off, 64));

    float sm[4] = {0.f, 0.f, 0.f, 0.f};
    #pragma unroll
    for (int mt = 0; mt < 14; ++mt)
        #pragma unroll
        for (int rg = 0; rg < 4; ++rg) {
            float p = exp2f((sacc[mt][rg] - mx[rg]) * 1.44269504f);
            sm[rg] += p;
            p_base[(g * 4 + rg) * 232 + mt * 16 + c16] = f2bf(p);
        }

    // batch 3: all 28 V fragments (overlap with sum-reduce)
    bf16x8 vbf[7][4];
    #pragma unroll
    for (int ks = 0; ks < 7; ++ks)
        #pragma unroll
        for (int j = 0; j < 4; ++j)
            vbf[ks][j] = *(const bf16x8*)(vt_ws +
                ((size_t)bh * HD + j * 16 + c16) * MPAD + ks * 32 + g * 8);

    #pragma unroll
    for (int off = 1; off < 16; off <<= 1)
        #pragma unroll
        for (int rg = 0; rg < 4; ++rg)
            sm[rg] += __shfl_xor(sm[rg], off, 64);

    f32x4 oacc[4] = {};
    __builtin_amdgcn_s_setprio(1);
    #pragma unroll
    for (int ks = 0; ks < 7; ++ks) {
        const int kk = ks * 32 + g * 8;
        bf16x8 pa = *(const bf16x8*)&p_base[c16 * 232 + kk];
        #pragma unroll
        for (int j = 0; j < 4; ++j)
            oacc[j] = __builtin_amdgcn_mfma_f32_16x16x32_bf16(pa, vbf[ks][j], oacc[j], 0, 0, 0);
    }
    __builtin_amdgcn_s_setprio(0);

    // O: oacc -> own slab [16][72] -> 16 full-line 128B stores
    #pragma unroll
    for (int rg = 0; rg < 4; ++rg) {
        const float inv = 1.0f / sm[rg];
        #pragma unroll
        for (int j = 0; j < 4; ++j)
            p_base[(g * 4 + rg) * 72 + j * 16 + c16] = f2bf(oacc[j][rg] * inv);
    }
    const size_t obase = ((size_t)b * NTOK) * DIMC + h * HD + lane;
    #pragma unroll
    for (int r = 0; r < 16; ++r) {
        const int n = rt * 16 + r;
        if (n < NTOK)
            o_ws[obase + (size_t)n * DIMC] = p_base[r * 72 + lane];
    }
}

// ---------------------------------------------------------------------------
// Kernel 3: proj GEMM (o_ws bf16 @ pw_bf^T + proj_b) -> fp32 out; 2-phase
// dbuf, 32x32x16 inner loop. Grid: 594 flat blocks, XCD swizzle (q=74, r=2).
// ---------------------------------------------------------------------------
__global__ __launch_bounds__(256) void proj_gemm_kernel(
    const short* __restrict__ a, const short* __restrict__ wb,
    const float* __restrict__ pb, float* __restrict__ out) {
    __shared__ __align__(16) short lds_a0[128 * 64];
    __shared__ __align__(16) short lds_a1[128 * 64];
    __shared__ __align__(16) short lds_b0[128 * 64];
    __shared__ __align__(16) short lds_b1[128 * 64];
    const int tid  = threadIdx.x;
    const int lane = tid & 63;
    const int wv   = tid >> 6;
    const int wr   = wv >> 1, wc = wv & 1;
    // XCD-bijective decode: nwg=594, q=74, r=2
    const int flat = blockIdx.x;
    const int xcd  = flat & 7, pos = flat >> 3;
    const int swz  = ((xcd < 2) ? xcd * 75 : 150 + (xcd - 2) * 74) + pos;
    const int bm   = swz / 6, bn = swz - bm * 6;
    const int r31  = lane & 31, kh = lane >> 5, l7 = lane & 7;

    f32x16 acc[2][2] = {};

    const int lrow = lane >> 3;
    const int lcol = ((lane & 7) ^ lrow) * 8;     // inverse-swizzled source col
    const short* aptr[4];
    const short* bptr[4];
    #pragma unroll
    for (int i = 0; i < 4; ++i) {
        const int r  = (wv * 4 + i) * 8 + lrow;
        int gr = bm * 128 + r; if (gr > M_TOK - 1) gr = M_TOK - 1;
        aptr[i] = a  + (size_t)gr * DIMC + lcol;
        bptr[i] = wb + (size_t)(bn * 128 + r) * DIMC + lcol;
    }

    STAGE(lds_a0, lds_b0, 0);
    __syncthreads();
    #pragma unroll
    for (int kp = 0; kp < 6; ++kp) {
        STAGE(lds_a1, lds_b1, 2 * kp + 1);
        COMPUTE(lds_a0, lds_b0);
        __syncthreads();
        if (kp < 5) { STAGE(lds_a0, lds_b0, 2 * kp + 2); }
        COMPUTE(lds_a1, lds_b1);
        if (kp < 5) __syncthreads();
    }

    // epilogue: 32x32 C/D layout; stores cover 2 rows x 32 cols (2x128B segs)
    #pragma unroll
    for (int i = 0; i < 2; ++i)
        #pragma unroll
        for (int j = 0; j < 2; ++j) {
            const int c = bn * 128 + wc * 64 + j * 32 + r31;
            const float bias = pb[c];
            #pragma unroll
            for (int reg = 0; reg < 16; ++reg) {
                const int tt = bm * 128 + CROW(i, reg);
                if (tt >= M_TOK) continue;
                out[(size_t)tt * DIMC + c] = acc[i][j][reg] + bias;
            }
        }
}

// ---------------------------------------------------------------------------
// Workspace layout (bytes):
//   q_ws   : 19,368,192   @ 0
//   k_ws   : 19,368,192   @ 19,368,192
//   vt_ws  : 22,020,096   @ 38,736,384
//   x_bf / o_ws : 19,365,888 @ 60,756,480  (aliased: x_bf dead before attn)
//   rpbL   :  1,118,208   @ 80,122,368  (bf16, C-frag order)
//   w_bf   :  3,538,944   @ 81,985,200
//   pw_bf  :  1,179,648   @ 85,524,144    total 86,703,792
// ---------------------------------------------------------------------------
extern "C" void kernel_launch(void* const* d_in, const int* in_sizes, int n_in,
                              void* d_out, int out_size, void* d_ws, size_t ws_size,
                              hipStream_t stream) {
    const float* x       = (const float*)d_in[0];
    const float* qkv_w   = (const float*)d_in[1];
    const float* q_bias  = (const float*)d_in[2];
    const float* v_bias  = (const float*)d_in[3];
    const float* rpb_tab = (const float*)d_in[4];
    const float* proj_w  = (const float*)d_in[5];
    const float* proj_b  = (const float*)d_in[6];
    const int*   rel_idx = (const int*)d_in[7];
    float* out = (float*)d_out;

    char* ws = (char*)d_ws;
    short* q_ws     = (short*)(ws);
    short* k_ws     = (short*)(ws + 19368192);
    short* vt_ws    = (short*)(ws + 38736384);
    short* x_bf     = (short*)(ws + 60756480);   // aliased with o_ws
    short* o_ws     = (short*)(ws + 60756480);
    short* rpbL     = (short*)(ws + 80122368);
    short* w_bf     = (short*)(ws + 81985200);
    short* pw_bf    = (short*)(ws + 85524144);

    prep_kernel<<<CVT_BLK + RPB_BLK, 256, 0, stream>>>(
        x, x_bf, qkv_w, w_bf, proj_w, pw_bf, rpb_tab, rel_idx, rpbL);

    qkv_gemm_kernel<<<1782, 256, 0, stream>>>(x_bf, w_bf, q_bias, v_bias,
                                              q_ws, k_ws, vt_ws);
    attn_kernel<<<2496, 256, 0, stream>>>(q_ws, k_ws, vt_ws, rpbL, o_ws);
    proj_gemm_kernel<<<594, 256, 0, stream>>>(o_ws, pw_bf, proj_b, out);
}

// Round 17
// 181.512 us; speedup vs baseline: 1.0560x; 1.0560x over previous
//
#include <hip/hip_runtime.h>
#include <hip/hip_bf16.h>

// Problem constants
#define HEADS   12
#define HD      64
#define NTOK    197          // N_PATCH + 1
#define BATCH   64
#define M_TOK   (BATCH*NTOK) // 12608
#define DIMC    768
#define NPAIR   (NTOK*NTOK)  // 38809
#define MPAD    224          // key/m dimension padded to 7*32

typedef __attribute__((ext_vector_type(8))) short bf16x8;  // 8 bf16 (4 VGPRs)
typedef __attribute__((ext_vector_type(4))) short s16x4;
typedef __attribute__((ext_vector_type(4))) float f32x4;

// fp32 -> bf16 round-to-nearest-even
static __device__ __forceinline__ short f2bf(float f) {
    unsigned u = __float_as_uint(f);
    unsigned r = (u + 0x7FFFu + ((u >> 16) & 1u)) >> 16;
    return (short)r;
}
static __device__ __forceinline__ float bf2f(short s) {
    return __uint_as_float(((unsigned)(unsigned short)s) << 16);
}

// ---------------------------------------------------------------------------
// Kernel 0: merged prep — fp32->bf16 bulk convert of x/qkv_w/proj_w PLUS the
// rpbL gather (pre-swizzled into MFMA C-fragment order, bf16). One launch.
// ---------------------------------------------------------------------------
#define NX (M_TOK * DIMC)        // 9,682,944
#define NW (3 * DIMC * DIMC)     // 1,769,472
#define NP (DIMC * DIMC)         //   589,824
#define NRPB (HEADS * 13 * 56 * 64)          // 559,104
#define CVT_N   ((NX + NW + NP) / 4)         // 3,010,560 float4s
#define CVT_BLK ((CVT_N + 255) / 256)        // 11,760
#define RPB_BLK ((NRPB + 255) / 256)         // 2,184
__global__ void prep_kernel(const float* __restrict__ s0, short* __restrict__ d0,
                            const float* __restrict__ s1, short* __restrict__ d1,
                            const float* __restrict__ s2, short* __restrict__ d2,
                            const float* __restrict__ table,
                            const int* __restrict__ idx,
                            short* __restrict__ rpbl) {
    if (blockIdx.x < CVT_BLK) {
        int i = (blockIdx.x * 256 + threadIdx.x) * 4;
        const float* s; short* d;
        if (i < NX)                { s = s0 + i; d = d0 + i; }
        else if (i < NX + NW)      { s = s1 + (i - NX); d = d1 + (i - NX); }
        else if (i < NX + NW + NP) { s = s2 + (i - NX - NW); d = d2 + (i - NX - NW); }
        else return;
        const float4 v = *(const float4*)s;
        s16x4 b; b[0] = f2bf(v.x); b[1] = f2bf(v.y); b[2] = f2bf(v.z); b[3] = f2bf(v.w);
        *(s16x4*)d = b;
    } else {
        int i = (blockIdx.x - CVT_BLK) * 256 + threadIdx.x;
        if (i >= NRPB) return;
        const int lane = i & 63;
        const int q    = (i >> 6) % 56;
        const int rt   = ((i >> 6) / 56) % 13;
        const int h    = (i >> 6) / (56 * 13);
        const int rg = q / 14, mt = q - rg * 14;
        const int g = lane >> 4, c16 = lane & 15;
        const int n = rt * 16 + g * 4 + rg;
        const int m = mt * 16 + c16;
        float v = 0.f;
        if (n < NTOK && m < NTOK) v = table[idx[n * NTOK + m] * HEADS + h];
        rpbl[i] = f2bf(v);
    }
}

// ---------------------------------------------------------------------------
// GEMM building blocks (R13 config — measured best): 128x128 tile, BK=64,
// 4 waves, 2-phase double-buffered staging, involution LDS swizzle.
// ---------------------------------------------------------------------------
#define STAGE(LA, LB, kt)                                                       \
    _Pragma("unroll")                                                           \
    for (int i = 0; i < 4; ++i) {                                               \
        __builtin_amdgcn_global_load_lds(                                       \
            (const __attribute__((address_space(1))) void*)(aptr[i] + (kt) * 64),\
            (__attribute__((address_space(3))) void*)&(LA)[(wv * 4 + i) * 512], \
            16, 0, 0);                                                          \
        __builtin_amdgcn_global_load_lds(                                       \
            (const __attribute__((address_space(1))) void*)(bptr[i] + (kt) * 64),\
            (__attribute__((address_space(3))) void*)&(LB)[(wv * 4 + i) * 512], \
            16, 0, 0);                                                          \
    }

#define COMPUTE(LA, LB)                                                         \
    _Pragma("unroll")                                                           \
    for (int ks = 0; ks < 2; ++ks) {                                            \
        bf16x8 af[4], bfr[4];                                                   \
        const int kk = (((ks * 4 + g) ^ (c16 & 7)) << 3);   /* swizzled read */ \
        _Pragma("unroll")                                                       \
        for (int i = 0; i < 4; ++i)                                             \
            af[i] = *(const bf16x8*)&(LA)[(wr * 64 + i * 16 + c16) * 64 + kk];  \
        _Pragma("unroll")                                                       \
        for (int j = 0; j < 4; ++j)                                             \
            bfr[j] = *(const bf16x8*)&(LB)[(wc * 64 + j * 16 + c16) * 64 + kk]; \
        _Pragma("unroll")                                                       \
        for (int i = 0; i < 4; ++i)                                             \
            _Pragma("unroll")                                                   \
            for (int j = 0; j < 4; ++j)                                         \
                acc[i][j] = __builtin_amdgcn_mfma_f32_16x16x32_bf16(            \
                    af[i], bfr[j], acc[i][j], 0, 0, 0);                         \
    }

// ---------------------------------------------------------------------------
// Kernel 1: QKV GEMM (bf16 in). q/k/v uniform per bn (0-5 q, 6-11 k, 12-17 v).
// All epilogue paths transpose through LDS (full-line stores, wave-uniform
// /197). Grid: 1782 flat blocks, m204 bijective XCD swizzle (q=222, r=6).
// ---------------------------------------------------------------------------
__global__ __launch_bounds__(256) void qkv_gemm_kernel(
    const short* __restrict__ xb, const short* __restrict__ wb,
    const float* __restrict__ qb, const float* __restrict__ vb,
    short* __restrict__ q_ws, short* __restrict__ k_ws,
    short* __restrict__ vt_ws) {
    __shared__ __align__(16) short lds_a0[128 * 64];
    __shared__ __align__(16) short lds_a1[128 * 64];
    __shared__ __align__(16) short lds_bb[2 * 128 * 64];   // b0 = +0, b1 = +8192
    const int tid  = threadIdx.x;
    const int lane = tid & 63;
    const int wv   = tid >> 6;           // 0..3
    const int wr   = wv >> 1, wc = wv & 1;
    // XCD-bijective decode: nwg=1782, q=222, r=6
    const int flat = blockIdx.x;
    const int xcd  = flat & 7, pos = flat >> 3;
    const int swz  = ((xcd < 6) ? xcd * 223 : 1338 + (xcd - 6) * 222) + pos;
    const int bm   = swz / 18, bn = swz - bm * 18;
    const int g    = lane >> 4, c16 = lane & 15;

    f32x4 acc[4][4] = {};

    const int lrow = lane >> 3;
    const int lcol = ((lane & 7) ^ lrow) * 8;     // inverse-swizzled source col
    const short* aptr[4];
    const short* bptr[4];
    #pragma unroll
    for (int i = 0; i < 4; ++i) {
        const int r  = (wv * 4 + i) * 8 + lrow;
        int gr = bm * 128 + r; if (gr > M_TOK - 1) gr = M_TOK - 1;
        aptr[i] = xb + (size_t)gr * DIMC + lcol;
        bptr[i] = wb + (size_t)(bn * 128 + r) * DIMC + lcol;
    }

    STAGE(lds_a0, lds_bb, 0);
    __syncthreads();
    #pragma unroll
    for (int kp = 0; kp < 6; ++kp) {
        STAGE(lds_a1, (lds_bb + 8192), 2 * kp + 1);
        COMPUTE(lds_a0, lds_bb);
        __syncthreads();
        if (kp < 5) { STAGE(lds_a0, lds_bb, 2 * kp + 2); }
        COMPUTE(lds_a1, (lds_bb + 8192));
        if (kp < 5) __syncthreads();
    }

    // epilogue: C/D layout col = lane&15, row = (lane>>4)*4 + reg  [m89-verified]
    __syncthreads();                  // all waves done reading lds_bb
    short* t = lds_bb;
    if (bn < 12) {
        const int isq = (bn < 6);
        // Phase A: acc -> t[tok*128 + (col ^ ((tok>>2)&3)<<4)]  (+bias/scale)
        #pragma unroll
        for (int j = 0; j < 4; ++j) {
            const int col = wc * 64 + j * 16 + c16;
            const int r   = isq ? bn * 128 + col : bn * 128 + col - DIMC;
            const float bias = isq ? qb[r] : 0.0f;
            #pragma unroll
            for (int i = 0; i < 4; ++i) {
                const int tok0 = wr * 64 + i * 16 + (g << 2);
                #pragma unroll
                for (int rg = 0; rg < 4; ++rg) {
                    const int tok = tok0 + rg;
                    const int sw  = ((tok >> 2) & 3) << 4;
                    float val = acc[i][j][rg];
                    if (isq) val = (val + bias) * 0.125f;
                    t[tok * 128 + (col ^ sw)] = f2bf(val);
                }
            }
        }
        __syncthreads();
        // Phase B: wave wv streams token rows wv*32..+31; lane = d; 128B stores.
        short* dst = isq ? q_ws : k_ws;
        const int rbase = isq ? bn * 128 : bn * 128 - DIMC;
        for (int tr = 0; tr < 32; ++tr) {
            const int tok = wv * 32 + tr;
            const int tt  = bm * 128 + tok;
            if (tt >= M_TOK) continue;
            const int bb = tt / NTOK, nn = tt - bb * NTOK;     // wave-uniform
            const int sw = ((tok >> 2) & 3) << 4;
            #pragma unroll
            for (int half = 0; half < 2; ++half) {
                const int col = half * 64 + lane;
                const int h   = (rbase + half * 64) >> 6;      // lane<64: no carry
                dst[(((size_t)bb * HEADS + h) * NTOK + nn) * HD + lane] =
                    t[tok * 128 + (col ^ sw)];
            }
        }
    } else {
        // v-block: Phase A: acc -> t[col*128 + (tok ^ (col&7)<<3)] (+bias).
        #pragma unroll
        for (int i = 0; i < 4; ++i) {
            const int lt0 = wr * 64 + i * 16 + (g << 2);
            #pragma unroll
            for (int j = 0; j < 4; ++j) {
                const int col  = wc * 64 + j * 16 + c16;
                const int sw   = (col & 7) << 3;
                const float bias = vb[(bn - 12) * 128 + col];
                #pragma unroll
                for (int rg = 0; rg < 4; ++rg)
                    t[col * 128 + ((lt0 + rg) ^ sw)] = f2bf(acc[i][j][rg] + bias);
            }
        }
        __syncthreads();
        // Phase B: wave wv streams cols wv,wv+4,...; 64 lanes = 64 consecutive
        // tokens -> contiguous 128B stores.
        for (int cc = 0; cc < 32; ++cc) {
            const int col = cc * 4 + wv;
            const int sw  = (col & 7) << 3;
            const int r   = bn * 128 + col - 1536;
            const int h   = r >> 6, d = r & 63;
            #pragma unroll
            for (int half = 0; half < 2; ++half) {
                const int lt = lane + half * 64;
                const int tt = bm * 128 + lt;
                if (tt < M_TOK) {
                    const int b = tt / NTOK, n = tt - b * NTOK;
                    vt_ws[(((size_t)b * HEADS + h) * HD + d) * MPAD + n] =
                        t[col * 128 + (lt ^ sw)];
                }
            }
        }
    }
}

// ---------------------------------------------------------------------------
// Kernel 2: attention. 4 independent waves per 256-thread block; XCD locality
// decode; register-batched K / rpbL / V loads; T5 setprio around the MFMA
// clusters; O via LDS transpose. grid = 2496 = 312 * 8.
// ---------------------------------------------------------------------------
__global__ __launch_bounds__(256) void attn_kernel(
    const short* __restrict__ q_ws, const short* __restrict__ k_ws,
    const short* __restrict__ vt_ws, const short* __restrict__ rpbL,
    short* __restrict__ o_ws) {
    __shared__ __align__(16) short p_lds[4 * 3712];   // 4 slabs of 16*232
    const int lane = threadIdx.x & 63;
    const int wv   = threadIdx.x >> 6;
    const int id   = blockIdx.x;
    const int slot = id & 7;                          // XCD slot
    const int w    = (id >> 3) * 4 + wv;              // 0..1247 within slot
    const int bhl  = w / 13;                          // 0..95
    const int rt   = w - bhl * 13;                    // 0..12
    const int bh   = bhl * 8 + slot;                  // 0..767 (bijective)
    const int b    = bh / HEADS, h = bh - b * HEADS;
    const int g    = lane >> 4, c16 = lane & 15;
    short* p_base = p_lds + wv * 3712;

    bf16x8 qa0, qa1;
    {
        const size_t base = ((size_t)bh * NTOK + (rt * 16 + c16)) * HD + g * 8;
        qa0 = *(const bf16x8*)(q_ws + base);
        qa1 = *(const bf16x8*)(q_ws + base + 32);
    }

    // batch 1: all 28 K fragments (independent -> one latency)
    bf16x8 kb0[14], kb1[14];
    #pragma unroll
    for (int mt = 0; mt < 14; ++mt) {
        const size_t base = ((size_t)bh * NTOK + (mt * 16 + c16)) * HD + g * 8;
        kb0[mt] = *(const bf16x8*)(k_ws + base);
        kb1[mt] = *(const bf16x8*)(k_ws + base + 32);
    }

    f32x4 sacc[14];
    #pragma unroll
    for (int t = 0; t < 14; ++t) sacc[t] = (f32x4){0.f, 0.f, 0.f, 0.f};
    __builtin_amdgcn_s_setprio(1);
    #pragma unroll
    for (int mt = 0; mt < 14; ++mt) {
        sacc[mt] = __builtin_amdgcn_mfma_f32_16x16x32_bf16(qa0, kb0[mt], sacc[mt], 0, 0, 0);
        sacc[mt] = __builtin_amdgcn_mfma_f32_16x16x32_bf16(qa1, kb1[mt], sacc[mt], 0, 0, 0);
    }
    __builtin_amdgcn_s_setprio(0);

    // batch 2: 56 coalesced bf16 rpb lines (pre-swizzled to C-frag layout)
    float rp[4][14];
    {
        const short* rb = rpbL + (((size_t)h * 13 + rt) * 56) * 64 + lane;
        #pragma unroll
        for (int rg = 0; rg < 4; ++rg)
            #pragma unroll
            for (int mt = 0; mt < 14; ++mt)
                rp[rg][mt] = bf2f(rb[(rg * 14 + mt) * 64]);
    }

    float mx[4] = {-1e30f, -1e30f, -1e30f, -1e30f};
    #pragma unroll
    for (int rg = 0; rg < 4; ++rg) {
        const int n = rt * 16 + g * 4 + rg;
        #pragma unroll
        for (int mt = 0; mt < 14; ++mt) {
            const int m = mt * 16 + c16;
            float s = (n < NTOK && m < NTOK) ? sacc[mt][rg] + rp[rg][mt] : -1e30f;
            sacc[mt][rg] = s;
            mx[rg] = fmaxf(mx[rg], s);
        }
    }
    #pragma unroll
    for (int off = 1; off < 16; off <<= 1)
        #pragma unroll
        for (int rg = 0; rg < 4; ++rg)
            mx[rg] = fmaxf(mx[rg], __shfl_xor(mx[rg], off, 64));

    float sm[4] = {0.f, 0.f, 0.f, 0.f};
    #pragma unroll
    for (int mt = 0; mt < 14; ++mt)
        #pragma unroll
        for (int rg = 0; rg < 4; ++rg) {
            float p = exp2f((sacc[mt][rg] - mx[rg]) * 1.44269504f);
            sm[rg] += p;
            p_base[(g * 4 + rg) * 232 + mt * 16 + c16] = f2bf(p);
        }

    // batch 3: all 28 V fragments (overlap with sum-reduce)
    bf16x8 vbf[7][4];
    #pragma unroll
    for (int ks = 0; ks < 7; ++ks)
        #pragma unroll
        for (int j = 0; j < 4; ++j)
            vbf[ks][j] = *(const bf16x8*)(vt_ws +
                ((size_t)bh * HD + j * 16 + c16) * MPAD + ks * 32 + g * 8);

    #pragma unroll
    for (int off = 1; off < 16; off <<= 1)
        #pragma unroll
        for (int rg = 0; rg < 4; ++rg)
            sm[rg] += __shfl_xor(sm[rg], off, 64);

    f32x4 oacc[4] = {};
    __builtin_amdgcn_s_setprio(1);
    #pragma unroll
    for (int ks = 0; ks < 7; ++ks) {
        const int kk = ks * 32 + g * 8;
        bf16x8 pa = *(const bf16x8*)&p_base[c16 * 232 + kk];
        #pragma unroll
        for (int j = 0; j < 4; ++j)
            oacc[j] = __builtin_amdgcn_mfma_f32_16x16x32_bf16(pa, vbf[ks][j], oacc[j], 0, 0, 0);
    }
    __builtin_amdgcn_s_setprio(0);

    // O: oacc -> own slab [16][72] -> 16 full-line 128B stores
    #pragma unroll
    for (int rg = 0; rg < 4; ++rg) {
        const float inv = 1.0f / sm[rg];
        #pragma unroll
        for (int j = 0; j < 4; ++j)
            p_base[(g * 4 + rg) * 72 + j * 16 + c16] = f2bf(oacc[j][rg] * inv);
    }
    const size_t obase = ((size_t)b * NTOK) * DIMC + h * HD + lane;
    #pragma unroll
    for (int r = 0; r < 16; ++r) {
        const int n = rt * 16 + r;
        if (n < NTOK)
            o_ws[obase + (size_t)n * DIMC] = p_base[r * 72 + lane];
    }
}

// ---------------------------------------------------------------------------
// Kernel 3: proj GEMM (o_ws bf16 @ pw_bf^T + proj_b) -> fp32 out; 2-phase dbuf
// (R13 config). Grid: 594 flat blocks, XCD swizzle (q=74, r=2).
// ---------------------------------------------------------------------------
__global__ __launch_bounds__(256) void proj_gemm_kernel(
    const short* __restrict__ a, const short* __restrict__ wb,
    const float* __restrict__ pb, float* __restrict__ out) {
    __shared__ __align__(16) short lds_a0[128 * 64];
    __shared__ __align__(16) short lds_a1[128 * 64];
    __shared__ __align__(16) short lds_b0[128 * 64];
    __shared__ __align__(16) short lds_b1[128 * 64];
    const int tid  = threadIdx.x;
    const int lane = tid & 63;
    const int wv   = tid >> 6;
    const int wr   = wv >> 1, wc = wv & 1;
    // XCD-bijective decode: nwg=594, q=74, r=2
    const int flat = blockIdx.x;
    const int xcd  = flat & 7, pos = flat >> 3;
    const int swz  = ((xcd < 2) ? xcd * 75 : 150 + (xcd - 2) * 74) + pos;
    const int bm   = swz / 6, bn = swz - bm * 6;
    const int g    = lane >> 4, c16 = lane & 15;

    f32x4 acc[4][4] = {};

    const int lrow = lane >> 3;
    const int lcol = ((lane & 7) ^ lrow) * 8;     // inverse-swizzled source col
    const short* aptr[4];
    const short* bptr[4];
    #pragma unroll
    for (int i = 0; i < 4; ++i) {
        const int r  = (wv * 4 + i) * 8 + lrow;
        int gr = bm * 128 + r; if (gr > M_TOK - 1) gr = M_TOK - 1;
        aptr[i] = a  + (size_t)gr * DIMC + lcol;
        bptr[i] = wb + (size_t)(bn * 128 + r) * DIMC + lcol;
    }

    STAGE(lds_a0, lds_b0, 0);
    __syncthreads();
    #pragma unroll
    for (int kp = 0; kp < 6; ++kp) {
        STAGE(lds_a1, lds_b1, 2 * kp + 1);
        COMPUTE(lds_a0, lds_b0);
        __syncthreads();
        if (kp < 5) { STAGE(lds_a0, lds_b0, 2 * kp + 2); }
        COMPUTE(lds_a1, lds_b1);
        if (kp < 5) __syncthreads();
    }

    #pragma unroll
    for (int i = 0; i < 4; ++i) {
        const int tbase = bm * 128 + wr * 64 + i * 16 + (g << 2);
        #pragma unroll
        for (int j = 0; j < 4; ++j) {
            const int c   = bn * 128 + wc * 64 + j * 16 + c16;
            const float bias = pb[c];
            #pragma unroll
            for (int rg = 0; rg < 4; ++rg) {
                const int tt = tbase + rg;
                if (tt >= M_TOK) continue;
                out[(size_t)tt * DIMC + c] = acc[i][j][rg] + bias;
            }
        }
    }
}

// ---------------------------------------------------------------------------
// Workspace layout (bytes):
//   q_ws   : 19,368,192   @ 0
//   k_ws   : 19,368,192   @ 19,368,192
//   vt_ws  : 22,020,096   @ 38,736,384
//   x_bf / o_ws : 19,365,888 @ 60,756,480  (aliased: x_bf dead before attn)
//   rpbL   :  1,118,208   @ 80,122,368  (bf16, C-frag order)
//   w_bf   :  3,538,944   @ 81,985,200
//   pw_bf  :  1,179,648   @ 85,524,144    total 86,703,792
// ---------------------------------------------------------------------------
extern "C" void kernel_launch(void* const* d_in, const int* in_sizes, int n_in,
                              void* d_out, int out_size, void* d_ws, size_t ws_size,
                              hipStream_t stream) {
    const float* x       = (const float*)d_in[0];
    const float* qkv_w   = (const float*)d_in[1];
    const float* q_bias  = (const float*)d_in[2];
    const float* v_bias  = (const float*)d_in[3];
    const float* rpb_tab = (const float*)d_in[4];
    const float* proj_w  = (const float*)d_in[5];
    const float* proj_b  = (const float*)d_in[6];
    const int*   rel_idx = (const int*)d_in[7];
    float* out = (float*)d_out;

    char* ws = (char*)d_ws;
    short* q_ws     = (short*)(ws);
    short* k_ws     = (short*)(ws + 19368192);
    short* vt_ws    = (short*)(ws + 38736384);
    short* x_bf     = (short*)(ws + 60756480);   // aliased with o_ws
    short* o_ws     = (short*)(ws + 60756480);
    short* rpbL     = (short*)(ws + 80122368);
    short* w_bf     = (short*)(ws + 81985200);
    short* pw_bf    = (short*)(ws + 85524144);

    prep_kernel<<<CVT_BLK + RPB_BLK, 256, 0, stream>>>(
        x, x_bf, qkv_w, w_bf, proj_w, pw_bf, rpb_tab, rel_idx, rpbL);

    qkv_gemm_kernel<<<1782, 256, 0, stream>>>(x_bf, w_bf, q_bias, v_bias,
                                              q_ws, k_ws, vt_ws);
    attn_kernel<<<2496, 256, 0, stream>>>(q_ws, k_ws, vt_ws, rpbL, o_ws);
    proj_gemm_kernel<<<594, 256, 0, stream>>>(o_ws, pw_bf, proj_b, out);
}